// Round 10
// baseline (205.720 us; speedup 1.0000x reference)
//
#include <hip/hip_runtime.h>
#include <hip/hip_bf16.h>

// SelfAttention: B=8, N=2048, D=512, fp32 in/out.
// No-max softmax: P = exp(S)*mask, l = rowsum(P), O = (P.V)/l.
// Pipeline: convert_all (+lde zero) -> qkv_gemm -> gemm_s -> gemm_o.
// CONFIG = r13 (best measured 197.4us) + qkv XCD batch-pinning (r14).
// Settled lessons: r7 full fusion = barrier-bound. r8/r12 tile growth on the
// 2-barrier form REGRESSES. r11: deep phase pipeline needs LONG K (gemm_o NT=32 ok;
// K=512 NT=8 regresses). r6 form (128^2, BK=64, 256thr, occ4) is the K=512 local
// optimum. r13 counter-lesson: XCD batch-pinning wins come from PRODUCER->CONSUMER
// L2 handoff across kernels (gemm_s's pinned P writes made pinned gemm_o faster,
// -15us net, even though gemm_s itself slowed 46->54).
// r14: extend the handoff chain back one link — qkv pinned by batch (bat=bid&7,
// rowblk=bat*16+(idx&15), colblk=idx>>4 outer): X-slice (2MB) L2-resident across 12
// colblk passes; Q/K/V of batch b retire into XCD b's L2, which pinned gemm_s then
// stages warm. Bodies untouched.
// ws (ushort elems): Pm[8*2048*2048] (Xb aliases head) | Wb[1536*512] | Qb | Kb
//   | Vtb[8*512*2048] | lde[16384 f32]  ~= 113.6 MB.

typedef __attribute__((ext_vector_type(8))) short short8;   // 8 x bf16
typedef __attribute__((ext_vector_type(4))) float f32x4;    // MFMA 16x16 acc

#define DEV __device__ __forceinline__
#define GLOBAL_AS __attribute__((address_space(1)))
#define LDS_AS __attribute__((address_space(3)))

static DEV ushort f2bs(float f) {  // fp32 -> bf16 bits, RNE
  union { float f; unsigned u; } x; x.f = f;
  unsigned r = (x.u + 0x7fffu + ((x.u >> 16) & 1u)) >> 16;
  return (ushort)r;
}

static DEV f32x4 mfma16(short8 a, short8 b, f32x4 c) {
  // C[m][n] += sum_k A[m][k]*B[n][k]
  return __builtin_amdgcn_mfma_f32_16x16x32_bf16(a, b, c, 0, 0, 0);
}

static DEV void async16(const void* g, void* l) {
  __builtin_amdgcn_global_load_lds((const GLOBAL_AS void*)g, (LDS_AS void*)l, 16, 0, 0);
}

// ---------------------------------------------------------------------------
// fp32->bf16 converts (weights, X) + lde zeroing, one kernel.
__global__ void convert_all(const float* __restrict__ wq, const float* __restrict__ wk,
                            const float* __restrict__ wv, const float* __restrict__ x,
                            ushort* __restrict__ wb, ushort* __restrict__ xb,
                            float* __restrict__ lde) {
  int i = blockIdx.x * 256 + threadIdx.x;
  if (i >= 2293760) {                       // lde tail: 4096 float4 groups
    int off = (i - 2293760) * 4;
    float4 z; z.x = 0.f; z.y = 0.f; z.z = 0.f; z.w = 0.f;
    *(float4*)(lde + off) = z;
    return;
  }
  const float* src;
  ushort* dst;
  if (i < 196608) {
    int which = i >> 16;
    int off = (i & 65535) * 4;
    src = ((which == 0) ? wq : (which == 1) ? wk : wv) + off;
    dst = wb + (size_t)which * 262144 + off;
  } else {
    int off = (i - 196608) * 4;
    src = x + off;
    dst = xb + off;
  }
  float4 v = *(const float4*)src;
  ushort4 o;
  o.x = f2bs(v.x); o.y = f2bs(v.y); o.z = f2bs(v.z); o.w = f2bs(v.w);
  *(ushort4*)dst = o;
}

// ---------------------------------------------------------------------------
// Shared K-loop (BK=64): stage A/B 128x64-bf16 tiles, swizzled, then 2 k-slices.
// As/Bs rows are 128B = 8 chunks of 16B; LDS chunk c holds global chunk c^(row&7).
#define KLOOP_STAGE(Aptr, lda, Bptr, ldb)                                      \
  do {                                                                         \
    _Pragma("unroll")                                                          \
    for (int t = 0; t < 8; t++) {                                              \
      int rowbase = (t & 3) * 32 + wave * 8;                                   \
      int r = rowbase + (lane >> 3);                                           \
      int gc = (lane & 7) ^ (r & 7);                                           \
      if (t < 4)                                                               \
        async16((Aptr) + (size_t)(rowblk * 128 + r) * (lda) + kb + gc * 8,     \
                &As[rowbase * 64]);                                            \
      else                                                                     \
        async16((Bptr) + (size_t)(colblk * 128 + r) * (ldb) + kb + gc * 8,     \
                &Bs[rowbase * 64]);                                            \
    }                                                                          \
  } while (0)

#define KLOOP_MFMA()                                                           \
  do {                                                                         \
    _Pragma("unroll")                                                          \
    for (int ks = 0; ks < 2; ks++) {                                           \
      short8 af[4], bfr[4];                                                    \
      _Pragma("unroll")                                                        \
      for (int t = 0; t < 4; t++) {                                            \
        int ra = wm * 64 + t * 16 + c16;                                       \
        int rb = wn * 64 + t * 16 + c16;                                       \
        af[t]  = *(const short8*)&As[ra * 64 + (((ks * 4 + quad) ^ (ra & 7)) * 8)]; \
        bfr[t] = *(const short8*)&Bs[rb * 64 + (((ks * 4 + quad) ^ (rb & 7)) * 8)]; \
      }                                                                        \
      _Pragma("unroll")                                                        \
      for (int mt = 0; mt < 4; mt++)                                           \
        _Pragma("unroll")                                                      \
        for (int nt = 0; nt < 4; nt++)                                         \
          acc[mt][nt] = mfma16(af[mt], bfr[nt], acc[mt][nt]);                  \
    }                                                                          \
  } while (0)

// ---------------------------------------------------------------------------
// Fused QKV GEMM: C[n][eg] = sum_d X[n][d]*W[eg][d] + bias, eg in [0,1536).
// eg<512 -> Q (scaled 1/sqrt(D)), <1024 -> K, else V^T [b][d][n].
// r14 grid: 1536 linear blocks; bat=bid&7 -> XCD pin (tokens of batch bat);
// rowblk = bat*16 + (idx&15), colblk = idx>>4 (outer -> X slice L2-resident).
__launch_bounds__(256, 4)
__global__ void qkv_gemm(const ushort* __restrict__ Xb, const ushort* __restrict__ Wb,
                         const float* __restrict__ bq, const float* __restrict__ bk,
                         const float* __restrict__ bv,
                         ushort* __restrict__ Qb, ushort* __restrict__ Kb,
                         ushort* __restrict__ Vtb) {
  const int bid = blockIdx.x;         // 0..1535
  const int bat = bid & 7;            // batch -> XCD pin
  const int idx = bid >> 3;           // 0..191
  const int rowblk = bat * 16 + (idx & 15);  // token tile 0..127 (batch-local)
  const int colblk = idx >> 4;        // 0..11  (output cols / 128)
  const int z = colblk >> 2;          // 0 Q, 1 K, 2 V

  __shared__ ushort S[2 * 128 * 64];  // 32 KB: As | Bs (and epilogue transpose tile)
  ushort* As = S;
  ushort* Bs = S + 128 * 64;

  const int tid = threadIdx.x;
  const int wave = tid >> 6, lane = tid & 63, quad = lane >> 4, c16 = lane & 15;
  const int wm = wave & 1, wn = wave >> 1;

  f32x4 acc[4][4];
#pragma unroll
  for (int mt = 0; mt < 4; mt++)
#pragma unroll
    for (int nt = 0; nt < 4; nt++) acc[mt][nt] = (f32x4)0.0f;

  for (int kb = 0; kb < 512; kb += 64) {
    __syncthreads();
    KLOOP_STAGE(Xb, 512, Wb, 512);
    __syncthreads();
    KLOOP_MFMA();
  }

  const float* bias = (z == 0) ? bq : (z == 1) ? bk : bv;
  float bvals[4];
#pragma unroll
  for (int nt = 0; nt < 4; nt++) {
    int eg = colblk * 128 + wn * 64 + nt * 16 + c16;
    bvals[nt] = bias[eg & 511];
  }
  const float sc = (z == 0) ? 0.044194173824159216f : 1.0f;   // 1/sqrt(512) into Q

  const int row0 = rowblk * 128 + wm * 64;
  const int col0 = colblk * 128 + wn * 64;
  if (z < 2) {
    ushort* O = (z == 0) ? Qb : Kb;
#pragma unroll
    for (int mt = 0; mt < 4; mt++)
#pragma unroll
      for (int nt = 0; nt < 4; nt++) {
        int el = (col0 + nt * 16 + c16) & 511;
#pragma unroll
        for (int r = 0; r < 4; r++) {
          int n = row0 + mt * 16 + quad * 4 + r;
          O[(size_t)n * 512 + el] = f2bs((acc[mt][nt][r] + bvals[nt]) * sc);
        }
      }
  } else {
    // V^T: transpose via LDS (dead As+Bs), then 64-B sector-complete streaming stores.
    __syncthreads();                   // all waves done reading As/Bs
    ushort* T = S;                     // T[el 0..127][n 0..127], chunk-xor swizzled
#pragma unroll
    for (int nt = 0; nt < 4; nt++) {
      int ell = wn * 64 + nt * 16 + c16;       // local el
#pragma unroll
      for (int mt = 0; mt < 4; mt++) {
        int n0l = wm * 64 + mt * 16 + quad * 4; // local n (4 consecutive via r)
        ushort4 o;
        o.x = f2bs(acc[mt][nt][0] + bvals[nt]);
        o.y = f2bs(acc[mt][nt][1] + bvals[nt]);
        o.z = f2bs(acc[mt][nt][2] + bvals[nt]);
        o.w = f2bs(acc[mt][nt][3] + bvals[nt]);
        *(ushort4*)&T[ell * 128 + (((n0l >> 3) ^ (ell & 15)) << 3) + (n0l & 4)] = o;
      }
    }
    __syncthreads();
    const int c4 = tid & 3, er = tid >> 2;      // 4 lanes per row -> 64B runs
    const int bb = rowblk >> 4;
    const int nbase = (rowblk & 15) * 128;
    const int elbase = (colblk & 3) * 128;
#pragma unroll
    for (int part = 0; part < 2; part++) {
      int ell = part * 64 + er;
      size_t ge = ((size_t)bb * 512 + elbase + ell) * 2048;
#pragma unroll
      for (int j2 = 0; j2 < 4; j2++) {
        int n0 = j2 * 32 + c4 * 8;              // ushort units within the 128-n tile
        short8 v = *(short8*)&T[ell * 128 + (((n0 >> 3) ^ (ell & 15)) << 3)];
        *(short8*)(Vtb + ge + nbase + n0) = v;
      }
    }
  }
}

// ---------------------------------------------------------------------------
// gemm_s: per batch, C[m=key][n=query] = K.Q^T (Q pre-scaled).  r6 body, r13 grid:
// 2048 linear blocks, b = bid&7 (XCD pin: batch's K+Q = 4MB = one L2),
// rowblk = (bid>>3)&15 (key tile), colblk = bid>>7 (query tile).
__launch_bounds__(256, 4)
__global__ void gemm_s(const ushort* __restrict__ Kb, const ushort* __restrict__ Qb,
                       const int* __restrict__ mask, ushort* __restrict__ Pm,
                       float* __restrict__ l) {
  const int bid = blockIdx.x;
  const int b = bid & 7;
  const int rowblk = (bid >> 3) & 15;   // key tile
  const int colblk = bid >> 7;          // query tile
  const ushort* A  = Kb + (size_t)b * 2048 * 512;
  const ushort* Bq = Qb + (size_t)b * 2048 * 512;

  __shared__ ushort S[2 * 128 * 64];  // 32 KB
  ushort* As = S;
  ushort* Bs = S + 128 * 64;

  const int tid = threadIdx.x;
  const int wave = tid >> 6, lane = tid & 63, quad = lane >> 4, c16 = lane & 15;
  const int wm = wave & 1, wn = wave >> 1;

  f32x4 acc[4][4];
#pragma unroll
  for (int mt = 0; mt < 4; mt++)
#pragma unroll
    for (int nt = 0; nt < 4; nt++) acc[mt][nt] = (f32x4)0.0f;

  for (int kb = 0; kb < 512; kb += 64) {
    __syncthreads();
    KLOOP_STAGE(A, 512, Bq, 512);
    __syncthreads();
    KLOOP_MFMA();
  }

  const int row0 = rowblk * 128 + wm * 64;   // key base (global in batch)
  const int col0 = colblk * 128 + wn * 64;   // query base
  float lpart[4] = {0.0f, 0.0f, 0.0f, 0.0f};

  __syncthreads();                 // all waves done reading As/Bs; reuse S
  ushort* T = S;                   // T[q 0..127][key 0..127], chunk-xor swizzled
#pragma unroll
  for (int mt = 0; mt < 4; mt++) {
    int key0 = row0 + mt * 16 + quad * 4;       // global key (for mask)
    int k0l  = wm * 64 + mt * 16 + quad * 4;    // local key
    int4 mv = *(const int4*)&mask[b * 2048 + key0];
    float mf0 = mv.x ? 1.0f : 0.0f, mf1 = mv.y ? 1.0f : 0.0f;
    float mf2 = mv.z ? 1.0f : 0.0f, mf3 = mv.w ? 1.0f : 0.0f;
#pragma unroll
    for (int nt = 0; nt < 4; nt++) {
      int ql = wn * 64 + nt * 16 + c16;         // local query
      float p0 = __expf(acc[mt][nt][0]) * mf0;
      float p1 = __expf(acc[mt][nt][1]) * mf1;
      float p2 = __expf(acc[mt][nt][2]) * mf2;
      float p3 = __expf(acc[mt][nt][3]) * mf3;
      ushort4 o;
      o.x = f2bs(p0); o.y = f2bs(p1); o.z = f2bs(p2); o.w = f2bs(p3);
      *(ushort4*)&T[ql * 128 + (((k0l >> 3) ^ (ql & 15)) << 3) + (k0l & 4)] = o;
      lpart[nt] += p0 + p1 + p2 + p3;
    }
  }
#pragma unroll
  for (int nt = 0; nt < 4; nt++) {
    float v = lpart[nt];
    v += __shfl_xor(v, 16, 64);
    v += __shfl_xor(v, 32, 64);
    if (quad == 0) atomicAdd(&l[b * 2048 + col0 + nt * 16 + c16], v);
  }
  __syncthreads();
  {
    const int c4 = tid & 3, er = tid >> 2;      // 4 lanes per q-row -> 64B runs
#pragma unroll
    for (int part = 0; part < 2; part++) {
      int ql = part * 64 + er;
      size_t gq = ((size_t)b * 2048 + colblk * 128 + ql) * 2048;
#pragma unroll
      for (int j2 = 0; j2 < 4; j2++) {
        int n0 = j2 * 32 + c4 * 8;              // ushort units within 128-key tile
        short8 v = *(short8*)&T[ql * 128 + (((n0 >> 3) ^ (ql & 15)) << 3)];
        *(short8*)(Pm + gq + rowblk * 128 + n0) = v;
      }
    }
  }
}

// ===========================================================================
// gemm_o phase machinery (r9-proven): BM=256 x BN=128, 8 waves, 96KB 2-deep LDS,
// per-tile fine phases + ONE counted vmcnt(6) per K-tile.
#define PH_ST_A(pp, kt, rd)                                                    \
  do {                                                                         \
    int rowbase_ = (rd) * 64 + wave * 8;                                       \
    int r_ = rowbase_ + (lane >> 3);                                           \
    int gc_ = (lane & 7) ^ (r_ & 7);                                           \
    async16(gA + (size_t)(arow0 + r_) * glda + (kt) * 64 + gc_ * 8,            \
            SdA + (pp) * 16384 + rowbase_ * 64);                               \
  } while (0)

#define PH_ST_B(pp, kt, rd)                                                    \
  do {                                                                         \
    int rowbase_ = (rd) * 64 + wave * 8;                                       \
    int r_ = rowbase_ + (lane >> 3);                                           \
    int gc_ = (lane & 7) ^ (r_ & 7);                                           \
    async16(gB + (size_t)(brow0 + r_) * gldb + (kt) * 64 + gc_ * 8,            \
            SdB + (pp) * 8192 + rowbase_ * 64);                                \
  } while (0)

#define PH_READ(pp, ks, afx, bfx)                                              \
  do {                                                                         \
    const ushort* Ap_ = SdA + (pp) * 16384;                                    \
    const ushort* Bp_ = SdB + (pp) * 8192;                                     \
    _Pragma("unroll")                                                          \
    for (int mf = 0; mf < 4; mf++) {                                           \
      int ra = wm * 64 + mf * 16 + c16;                                        \
      afx[mf] = *(const short8*)&Ap_[ra * 64 + ((((ks)*4 + quad) ^ (ra & 7)) * 8)]; \
    }                                                                          \
    _Pragma("unroll")                                                          \
    for (int nf = 0; nf < 4; nf++) {                                           \
      int rb = wn * 64 + nf * 16 + c16;                                        \
      bfx[nf] = *(const short8*)&Bp_[rb * 64 + ((((ks)*4 + quad) ^ (rb & 7)) * 8)]; \
    }                                                                          \
  } while (0)

#define PH_MFMA(afx, bfx, h)                                                   \
  do {                                                                         \
    __builtin_amdgcn_s_setprio(1);                                             \
    _Pragma("unroll")                                                          \
    for (int mf = (h) * 2; mf < (h) * 2 + 2; mf++)                             \
      _Pragma("unroll")                                                        \
      for (int nf = 0; nf < 4; nf++)                                           \
        acc[mf][nf] = mfma16(afx[mf], bfx[nf], acc[mf][nf]);                   \
    __builtin_amdgcn_s_setprio(0);                                             \
  } while (0)

#define PH_TILE(pp, kt, dostage)                                               \
  do {                                                                         \
    PH_READ(pp, 0, af0, bf0);                                                  \
    __builtin_amdgcn_s_barrier();                                              \
    asm volatile("s_waitcnt lgkmcnt(0)" ::: "memory");                         \
    __builtin_amdgcn_sched_barrier(0);                                         \
    PH_MFMA(af0, bf0, 0);                                                      \
    __builtin_amdgcn_s_barrier();                                              \
    PH_READ(pp, 1, af1, bf1);                                                  \
    __builtin_amdgcn_s_barrier();                                              \
    asm volatile("s_waitcnt lgkmcnt(0)" ::: "memory");                         \
    __builtin_amdgcn_sched_barrier(0);                                         \
    PH_MFMA(af0, bf0, 1);                                                      \
    __builtin_amdgcn_s_barrier();   /* all waves' buf-pp reads retired */      \
    if (dostage) { PH_ST_A(pp, (kt) + 2, 0); PH_ST_A(pp, (kt) + 2, 1);         \
                   PH_ST_A(pp, (kt) + 2, 2); }                                 \
    PH_MFMA(af1, bf1, 0);                                                      \
    __builtin_amdgcn_s_barrier();                                              \
    if (dostage) { PH_ST_A(pp, (kt) + 2, 3); PH_ST_B(pp, (kt) + 2, 0);         \
                   PH_ST_B(pp, (kt) + 2, 1); }                                 \
    PH_MFMA(af1, bf1, 1);                                                      \
    if (dostage) { asm volatile("s_waitcnt vmcnt(6)" ::: "memory"); }          \
    else         { asm volatile("s_waitcnt vmcnt(0)" ::: "memory"); }          \
    __builtin_amdgcn_sched_barrier(0);                                         \
    __builtin_amdgcn_s_barrier();   /* next tile resident for all waves */     \
  } while (0)

#define PH_PROLOGUE()                                                          \
  do {                                                                         \
    PH_ST_A(0, 0, 0); PH_ST_A(0, 0, 1); PH_ST_A(0, 0, 2); PH_ST_A(0, 0, 3);    \
    PH_ST_B(0, 0, 0); PH_ST_B(0, 0, 1);                                        \
    PH_ST_A(1, 1, 0); PH_ST_A(1, 1, 1); PH_ST_A(1, 1, 2); PH_ST_A(1, 1, 3);    \
    PH_ST_B(1, 1, 0); PH_ST_B(1, 1, 1);                                        \
    asm volatile("s_waitcnt vmcnt(6)" ::: "memory");                           \
    __builtin_amdgcn_sched_barrier(0);                                         \
    __builtin_amdgcn_s_barrier();                                              \
  } while (0)

// gemm_o, phase-scheduled (r9): per batch C[m=query][n=d] = P . V^T; /l, fp32 out.
__launch_bounds__(512, 2)
__global__ void gemm_o(const ushort* __restrict__ Pm, const ushort* __restrict__ Vtb,
                       const float* __restrict__ l, float* __restrict__ out) {
  const int bid = blockIdx.x;
  const int b = bid & 7;             // batch -> XCD pin
  const int rowblk = (bid >> 3) & 7; // query tile 0..7 (256 rows)
  const int colblk = bid >> 6;       // d tile 0..3 (128 cols)

  extern __shared__ ushort Sd[];     // 96 KB
  ushort* SdA = Sd;
  ushort* SdB = Sd + 32768;

  const int tid = threadIdx.x;
  const int wave = tid >> 6, lane = tid & 63, quad = lane >> 4, c16 = lane & 15;
  const int wm = wave >> 1, wn = wave & 1;   // 4M x 2N; per-wave 64q x 64d

  const ushort* gA = Pm + (size_t)b * 2048 * 2048;  const int glda = 2048;
  const int arow0 = rowblk * 256;
  const ushort* gB = Vtb + (size_t)b * 512 * 2048;  const int gldb = 2048;
  const int brow0 = colblk * 128;

  f32x4 acc[4][4];
#pragma unroll
  for (int mf = 0; mf < 4; mf++)
#pragma unroll
    for (int nf = 0; nf < 4; nf++) acc[mf][nf] = (f32x4)0.0f;

  PH_PROLOGUE();
  short8 af0[4], bf0[4], af1[4], bf1[4];
  for (int i = 0; i < 16; i++) {
    const int ds = (i < 15);
    PH_TILE(0, 2 * i, ds);
    PH_TILE(1, 2 * i + 1, ds);
  }

  // Epilogue: /l, fp32 out.
  const int row0 = rowblk * 256 + wm * 64;   // query
  const int col0 = colblk * 128 + wn * 64;   // d
  float linv[4][4];
#pragma unroll
  for (int mf = 0; mf < 4; mf++)
#pragma unroll
    for (int r = 0; r < 4; r++)
      linv[mf][r] = 1.0f / l[b * 2048 + row0 + mf * 16 + quad * 4 + r];
#pragma unroll
  for (int mf = 0; mf < 4; mf++)
#pragma unroll
    for (int nf = 0; nf < 4; nf++) {
      int col = col0 + nf * 16 + c16;
#pragma unroll
      for (int r = 0; r < 4; r++) {
        int row = row0 + mf * 16 + quad * 4 + r;
        out[((size_t)b * 2048 + row) * 512 + col] = acc[mf][nf][r] * linv[mf][r];
      }
    }
}

// ---------------------------------------------------------------------------
extern "C" void kernel_launch(void* const* d_in, const int* in_sizes, int n_in,
                              void* d_out, int out_size, void* d_ws, size_t ws_size,
                              hipStream_t stream) {
  (void)in_sizes; (void)n_in; (void)out_size; (void)ws_size;
  const float* X    = (const float*)d_in[0];
  const int*   mask = (const int*)d_in[1];
  const float* Wk   = (const float*)d_in[2];
  const float* bk   = (const float*)d_in[3];
  const float* Wq   = (const float*)d_in[4];
  const float* bq   = (const float*)d_in[5];
  const float* Wv   = (const float*)d_in[6];
  const float* bv   = (const float*)d_in[7];
  float* out = (float*)d_out;

  ushort* ws  = (ushort*)d_ws;
  ushort* Pm  = ws;                             // [8][2048][2048] bf16 (64 MB)
  ushort* Xb  = ws;                             // [16384][512] aliases Pm (dead after qkv)
  ushort* Wb  = ws + (size_t)33554432;          // [1536][512]  rows = [Wq;Wk;Wv]
  ushort* Qb  = Wb + (size_t)786432;            // [16384][512] pre-scaled
  ushort* Kb  = Qb + (size_t)8388608;           // [16384][512]
  ushort* Vtb = Kb + (size_t)8388608;           // [8][512][2048]
  float*  lde = (float*)(Vtb + (size_t)8388608);// [16384] softmax denominators

  convert_all<<<8976, 256, 0, stream>>>(Wq, Wk, Wv, X, Wb, Xb, lde);
  qkv_gemm<<<1536, 256, 0, stream>>>(Xb, Wb, bq, bk, bv, Qb, Kb, Vtb);
  gemm_s<<<2048, 256, 0, stream>>>(Kb, Qb, mask, Pm, lde);
  gemm_o<<<256, 512, 98304, stream>>>(Pm, Vtb, lde, out);
}

// Round 11
// 197.421 us; speedup vs baseline: 1.0420x; 1.0420x over previous
//
#include <hip/hip_runtime.h>
#include <hip/hip_bf16.h>

// SelfAttention: B=8, N=2048, D=512, fp32 in/out.
// No-max softmax: P = exp(S)*mask, l = rowsum(P), O = (P.V)/l.
// Pipeline: convert_all (+lde zero) -> qkv_gemm -> gemm_s -> gemm_o.
// CONFIG = r13 (best measured 197.4us) + NON-TEMPORAL bulk stores (r15).
// Settled lessons: r7 full fusion = barrier-bound. r8/r12 tile growth on the
// 2-barrier form REGRESSES. r11: deep phase pipeline needs LONG K. r6 form (128^2,
// BK=64, 256thr, occ4) is the K=512 local optimum. r13: XCD pin wins come from
// PRODUCER->CONSUMER L2 handoff (P: gemm_s -> gemm_o). r14 lesson: pinning a
// kernel's reads into the same L2 its writes flow through makes the write stream
// evict the read set (qkv pin: gemm_s 54->46 but qkv/gemm_o lost 16us net).
// r15: qkv back to (128,12) round-robin; P (64MB) and V^T (16MB) stores become
// __builtin_nontemporal_store (ISA `nt` — no L2 allocate): gemm_s's pinned K+Q
// stay L2-resident instead of being evicted by its own P stream; P/V^T live in
// the shared 256MB L3 for gemm_o's pipelined reads.
// ws (ushort elems): Pm[8*2048*2048] (Xb aliases head) | Wb[1536*512] | Qb | Kb
//   | Vtb[8*512*2048] | lde[16384 f32]  ~= 113.6 MB.

typedef __attribute__((ext_vector_type(8))) short short8;   // 8 x bf16
typedef __attribute__((ext_vector_type(4))) float f32x4;    // MFMA 16x16 acc

#define DEV __device__ __forceinline__
#define GLOBAL_AS __attribute__((address_space(1)))
#define LDS_AS __attribute__((address_space(3)))

static DEV ushort f2bs(float f) {  // fp32 -> bf16 bits, RNE
  union { float f; unsigned u; } x; x.f = f;
  unsigned r = (x.u + 0x7fffu + ((x.u >> 16) & 1u)) >> 16;
  return (ushort)r;
}

static DEV f32x4 mfma16(short8 a, short8 b, f32x4 c) {
  // C[m][n] += sum_k A[m][k]*B[n][k]
  return __builtin_amdgcn_mfma_f32_16x16x32_bf16(a, b, c, 0, 0, 0);
}

static DEV void async16(const void* g, void* l) {
  __builtin_amdgcn_global_load_lds((const GLOBAL_AS void*)g, (LDS_AS void*)l, 16, 0, 0);
}

// ---------------------------------------------------------------------------
// fp32->bf16 converts (weights, X) + lde zeroing, one kernel.
__global__ void convert_all(const float* __restrict__ wq, const float* __restrict__ wk,
                            const float* __restrict__ wv, const float* __restrict__ x,
                            ushort* __restrict__ wb, ushort* __restrict__ xb,
                            float* __restrict__ lde) {
  int i = blockIdx.x * 256 + threadIdx.x;
  if (i >= 2293760) {                       // lde tail: 4096 float4 groups
    int off = (i - 2293760) * 4;
    float4 z; z.x = 0.f; z.y = 0.f; z.z = 0.f; z.w = 0.f;
    *(float4*)(lde + off) = z;
    return;
  }
  const float* src;
  ushort* dst;
  if (i < 196608) {
    int which = i >> 16;
    int off = (i & 65535) * 4;
    src = ((which == 0) ? wq : (which == 1) ? wk : wv) + off;
    dst = wb + (size_t)which * 262144 + off;
  } else {
    int off = (i - 196608) * 4;
    src = x + off;
    dst = xb + off;
  }
  float4 v = *(const float4*)src;
  ushort4 o;
  o.x = f2bs(v.x); o.y = f2bs(v.y); o.z = f2bs(v.z); o.w = f2bs(v.w);
  *(ushort4*)dst = o;
}

// ---------------------------------------------------------------------------
// Shared K-loop (BK=64): stage A/B 128x64-bf16 tiles, swizzled, then 2 k-slices.
// As/Bs rows are 128B = 8 chunks of 16B; LDS chunk c holds global chunk c^(row&7).
#define KLOOP_STAGE(Aptr, lda, Bptr, ldb)                                      \
  do {                                                                         \
    _Pragma("unroll")                                                          \
    for (int t = 0; t < 8; t++) {                                              \
      int rowbase = (t & 3) * 32 + wave * 8;                                   \
      int r = rowbase + (lane >> 3);                                           \
      int gc = (lane & 7) ^ (r & 7);                                           \
      if (t < 4)                                                               \
        async16((Aptr) + (size_t)(rowblk * 128 + r) * (lda) + kb + gc * 8,     \
                &As[rowbase * 64]);                                            \
      else                                                                     \
        async16((Bptr) + (size_t)(colblk * 128 + r) * (ldb) + kb + gc * 8,     \
                &Bs[rowbase * 64]);                                            \
    }                                                                          \
  } while (0)

#define KLOOP_MFMA()                                                           \
  do {                                                                         \
    _Pragma("unroll")                                                          \
    for (int ks = 0; ks < 2; ks++) {                                           \
      short8 af[4], bfr[4];                                                    \
      _Pragma("unroll")                                                        \
      for (int t = 0; t < 4; t++) {                                            \
        int ra = wm * 64 + t * 16 + c16;                                       \
        int rb = wn * 64 + t * 16 + c16;                                       \
        af[t]  = *(const short8*)&As[ra * 64 + (((ks * 4 + quad) ^ (ra & 7)) * 8)]; \
        bfr[t] = *(const short8*)&Bs[rb * 64 + (((ks * 4 + quad) ^ (rb & 7)) * 8)]; \
      }                                                                        \
      _Pragma("unroll")                                                        \
      for (int mt = 0; mt < 4; mt++)                                           \
        _Pragma("unroll")                                                      \
        for (int nt = 0; nt < 4; nt++)                                         \
          acc[mt][nt] = mfma16(af[mt], bfr[nt], acc[mt][nt]);                  \
    }                                                                          \
  } while (0)

// ---------------------------------------------------------------------------
// Fused QKV GEMM: C[n][eg] = sum_d X[n][d]*W[eg][d] + bias, eg in [0,1536).
// eg<512 -> Q (scaled 1/sqrt(D)), <1024 -> K, else V^T [b][d][n].  r13 grid (128,12).
__launch_bounds__(256, 4)
__global__ void qkv_gemm(const ushort* __restrict__ Xb, const ushort* __restrict__ Wb,
                         const float* __restrict__ bq, const float* __restrict__ bk,
                         const float* __restrict__ bv,
                         ushort* __restrict__ Qb, ushort* __restrict__ Kb,
                         ushort* __restrict__ Vtb) {
  const int rowblk = blockIdx.x;      // 0..127 (token rows)
  const int colblk = blockIdx.y;      // 0..11  (output cols / 128)
  const int z = colblk >> 2;          // 0 Q, 1 K, 2 V

  __shared__ ushort S[2 * 128 * 64];  // 32 KB: As | Bs (and epilogue transpose tile)
  ushort* As = S;
  ushort* Bs = S + 128 * 64;

  const int tid = threadIdx.x;
  const int wave = tid >> 6, lane = tid & 63, quad = lane >> 4, c16 = lane & 15;
  const int wm = wave & 1, wn = wave >> 1;

  f32x4 acc[4][4];
#pragma unroll
  for (int mt = 0; mt < 4; mt++)
#pragma unroll
    for (int nt = 0; nt < 4; nt++) acc[mt][nt] = (f32x4)0.0f;

  for (int kb = 0; kb < 512; kb += 64) {
    __syncthreads();
    KLOOP_STAGE(Xb, 512, Wb, 512);
    __syncthreads();
    KLOOP_MFMA();
  }

  const float* bias = (z == 0) ? bq : (z == 1) ? bk : bv;
  float bvals[4];
#pragma unroll
  for (int nt = 0; nt < 4; nt++) {
    int eg = colblk * 128 + wn * 64 + nt * 16 + c16;
    bvals[nt] = bias[eg & 511];
  }
  const float sc = (z == 0) ? 0.044194173824159216f : 1.0f;   // 1/sqrt(512) into Q

  const int row0 = rowblk * 128 + wm * 64;
  const int col0 = colblk * 128 + wn * 64;
  if (z < 2) {
    ushort* O = (z == 0) ? Qb : Kb;
#pragma unroll
    for (int mt = 0; mt < 4; mt++)
#pragma unroll
      for (int nt = 0; nt < 4; nt++) {
        int el = (col0 + nt * 16 + c16) & 511;
#pragma unroll
        for (int r = 0; r < 4; r++) {
          int n = row0 + mt * 16 + quad * 4 + r;
          O[(size_t)n * 512 + el] = f2bs((acc[mt][nt][r] + bvals[nt]) * sc);
        }
      }
  } else {
    // V^T: transpose via LDS (dead As+Bs), then 64-B sector-complete nt stores
    // (V consumed only by gemm_o after gemm_s — don't pollute L2 with it).
    __syncthreads();                   // all waves done reading As/Bs
    ushort* T = S;                     // T[el 0..127][n 0..127], chunk-xor swizzled
#pragma unroll
    for (int nt = 0; nt < 4; nt++) {
      int ell = wn * 64 + nt * 16 + c16;       // local el
#pragma unroll
      for (int mt = 0; mt < 4; mt++) {
        int n0l = wm * 64 + mt * 16 + quad * 4; // local n (4 consecutive via r)
        ushort4 o;
        o.x = f2bs(acc[mt][nt][0] + bvals[nt]);
        o.y = f2bs(acc[mt][nt][1] + bvals[nt]);
        o.z = f2bs(acc[mt][nt][2] + bvals[nt]);
        o.w = f2bs(acc[mt][nt][3] + bvals[nt]);
        *(ushort4*)&T[ell * 128 + (((n0l >> 3) ^ (ell & 15)) << 3) + (n0l & 4)] = o;
      }
    }
    __syncthreads();
    const int c4 = tid & 3, er = tid >> 2;      // 4 lanes per row -> 64B runs
    const int bb = rowblk >> 4;
    const int nbase = (rowblk & 15) * 128;
    const int elbase = (colblk & 3) * 128;
#pragma unroll
    for (int part = 0; part < 2; part++) {
      int ell = part * 64 + er;
      size_t ge = ((size_t)bb * 512 + elbase + ell) * 2048;
#pragma unroll
      for (int j2 = 0; j2 < 4; j2++) {
        int n0 = j2 * 32 + c4 * 8;              // ushort units within the 128-n tile
        short8 v = *(short8*)&T[ell * 128 + (((n0 >> 3) ^ (ell & 15)) << 3)];
        __builtin_nontemporal_store(v, (short8*)(Vtb + ge + nbase + n0));
      }
    }
  }
}

// ---------------------------------------------------------------------------
// gemm_s: per batch, C[m=key][n=query] = K.Q^T (Q pre-scaled).  r6 body, r13 grid:
// 2048 linear blocks, b = bid&7 (XCD pin: batch's K+Q = 4MB = one L2),
// rowblk = (bid>>3)&15 (key tile), colblk = bid>>7 (query tile).
// r15: P stores are non-temporal -> the 64MB P stream no longer evicts K/Q from L2.
__launch_bounds__(256, 4)
__global__ void gemm_s(const ushort* __restrict__ Kb, const ushort* __restrict__ Qb,
                       const int* __restrict__ mask, ushort* __restrict__ Pm,
                       float* __restrict__ l) {
  const int bid = blockIdx.x;
  const int b = bid & 7;
  const int rowblk = (bid >> 3) & 15;   // key tile
  const int colblk = bid >> 7;          // query tile
  const ushort* A  = Kb + (size_t)b * 2048 * 512;
  const ushort* Bq = Qb + (size_t)b * 2048 * 512;

  __shared__ ushort S[2 * 128 * 64];  // 32 KB
  ushort* As = S;
  ushort* Bs = S + 128 * 64;

  const int tid = threadIdx.x;
  const int wave = tid >> 6, lane = tid & 63, quad = lane >> 4, c16 = lane & 15;
  const int wm = wave & 1, wn = wave >> 1;

  f32x4 acc[4][4];
#pragma unroll
  for (int mt = 0; mt < 4; mt++)
#pragma unroll
    for (int nt = 0; nt < 4; nt++) acc[mt][nt] = (f32x4)0.0f;

  for (int kb = 0; kb < 512; kb += 64) {
    __syncthreads();
    KLOOP_STAGE(A, 512, Bq, 512);
    __syncthreads();
    KLOOP_MFMA();
  }

  const int row0 = rowblk * 128 + wm * 64;   // key base (global in batch)
  const int col0 = colblk * 128 + wn * 64;   // query base
  float lpart[4] = {0.0f, 0.0f, 0.0f, 0.0f};

  __syncthreads();                 // all waves done reading As/Bs; reuse S
  ushort* T = S;                   // T[q 0..127][key 0..127], chunk-xor swizzled
#pragma unroll
  for (int mt = 0; mt < 4; mt++) {
    int key0 = row0 + mt * 16 + quad * 4;       // global key (for mask)
    int k0l  = wm * 64 + mt * 16 + quad * 4;    // local key
    int4 mv = *(const int4*)&mask[b * 2048 + key0];
    float mf0 = mv.x ? 1.0f : 0.0f, mf1 = mv.y ? 1.0f : 0.0f;
    float mf2 = mv.z ? 1.0f : 0.0f, mf3 = mv.w ? 1.0f : 0.0f;
#pragma unroll
    for (int nt = 0; nt < 4; nt++) {
      int ql = wn * 64 + nt * 16 + c16;         // local query
      float p0 = __expf(acc[mt][nt][0]) * mf0;
      float p1 = __expf(acc[mt][nt][1]) * mf1;
      float p2 = __expf(acc[mt][nt][2]) * mf2;
      float p3 = __expf(acc[mt][nt][3]) * mf3;
      ushort4 o;
      o.x = f2bs(p0); o.y = f2bs(p1); o.z = f2bs(p2); o.w = f2bs(p3);
      *(ushort4*)&T[ql * 128 + (((k0l >> 3) ^ (ql & 15)) << 3) + (k0l & 4)] = o;
      lpart[nt] += p0 + p1 + p2 + p3;
    }
  }
#pragma unroll
  for (int nt = 0; nt < 4; nt++) {
    float v = lpart[nt];
    v += __shfl_xor(v, 16, 64);
    v += __shfl_xor(v, 32, 64);
    if (quad == 0) atomicAdd(&l[b * 2048 + col0 + nt * 16 + c16], v);
  }
  __syncthreads();
  {
    const int c4 = tid & 3, er = tid >> 2;      // 4 lanes per q-row -> 64B runs
#pragma unroll
    for (int part = 0; part < 2; part++) {
      int ql = part * 64 + er;
      size_t gq = ((size_t)b * 2048 + colblk * 128 + ql) * 2048;
#pragma unroll
      for (int j2 = 0; j2 < 4; j2++) {
        int n0 = j2 * 32 + c4 * 8;              // ushort units within 128-key tile
        short8 v = *(short8*)&T[ql * 128 + (((n0 >> 3) ^ (ql & 15)) << 3)];
        __builtin_nontemporal_store(v, (short8*)(Pm + gq + rowblk * 128 + n0));
      }
    }
  }
}

// ===========================================================================
// gemm_o phase machinery (r9-proven): BM=256 x BN=128, 8 waves, 96KB 2-deep LDS,
// per-tile fine phases + ONE counted vmcnt(6) per K-tile.
#define PH_ST_A(pp, kt, rd)                                                    \
  do {                                                                         \
    int rowbase_ = (rd) * 64 + wave * 8;                                       \
    int r_ = rowbase_ + (lane >> 3);                                           \
    int gc_ = (lane & 7) ^ (r_ & 7);                                           \
    async16(gA + (size_t)(arow0 + r_) * glda + (kt) * 64 + gc_ * 8,            \
            SdA + (pp) * 16384 + rowbase_ * 64);                               \
  } while (0)

#define PH_ST_B(pp, kt, rd)                                                    \
  do {                                                                         \
    int rowbase_ = (rd) * 64 + wave * 8;                                       \
    int r_ = rowbase_ + (lane >> 3);                                           \
    int gc_ = (lane & 7) ^ (r_ & 7);                                           \
    async16(gB + (size_t)(brow0 + r_) * gldb + (kt) * 64 + gc_ * 8,            \
            SdB + (pp) * 8192 + rowbase_ * 64);                                \
  } while (0)

#define PH_READ(pp, ks, afx, bfx)                                              \
  do {                                                                         \
    const ushort* Ap_ = SdA + (pp) * 16384;                                    \
    const ushort* Bp_ = SdB + (pp) * 8192;                                     \
    _Pragma("unroll")                                                          \
    for (int mf = 0; mf < 4; mf++) {                                           \
      int ra = wm * 64 + mf * 16 + c16;                                        \
      afx[mf] = *(const short8*)&Ap_[ra * 64 + ((((ks)*4 + quad) ^ (ra & 7)) * 8)]; \
    }                                                                          \
    _Pragma("unroll")                                                          \
    for (int nf = 0; nf < 4; nf++) {                                           \
      int rb = wn * 64 + nf * 16 + c16;                                        \
      bfx[nf] = *(const short8*)&Bp_[rb * 64 + ((((ks)*4 + quad) ^ (rb & 7)) * 8)]; \
    }                                                                          \
  } while (0)

#define PH_MFMA(afx, bfx, h)                                                   \
  do {                                                                         \
    __builtin_amdgcn_s_setprio(1);                                             \
    _Pragma("unroll")                                                          \
    for (int mf = (h) * 2; mf < (h) * 2 + 2; mf++)                             \
      _Pragma("unroll")                                                        \
      for (int nf = 0; nf < 4; nf++)                                           \
        acc[mf][nf] = mfma16(afx[mf], bfx[nf], acc[mf][nf]);                   \
    __builtin_amdgcn_s_setprio(0);                                             \
  } while (0)

#define PH_TILE(pp, kt, dostage)                                               \
  do {                                                                         \
    PH_READ(pp, 0, af0, bf0);                                                  \
    __builtin_amdgcn_s_barrier();                                              \
    asm volatile("s_waitcnt lgkmcnt(0)" ::: "memory");                         \
    __builtin_amdgcn_sched_barrier(0);                                         \
    PH_MFMA(af0, bf0, 0);                                                      \
    __builtin_amdgcn_s_barrier();                                              \
    PH_READ(pp, 1, af1, bf1);                                                  \
    __builtin_amdgcn_s_barrier();                                              \
    asm volatile("s_waitcnt lgkmcnt(0)" ::: "memory");                         \
    __builtin_amdgcn_sched_barrier(0);                                         \
    PH_MFMA(af0, bf0, 1);                                                      \
    __builtin_amdgcn_s_barrier();   /* all waves' buf-pp reads retired */      \
    if (dostage) { PH_ST_A(pp, (kt) + 2, 0); PH_ST_A(pp, (kt) + 2, 1);         \
                   PH_ST_A(pp, (kt) + 2, 2); }                                 \
    PH_MFMA(af1, bf1, 0);                                                      \
    __builtin_amdgcn_s_barrier();                                              \
    if (dostage) { PH_ST_A(pp, (kt) + 2, 3); PH_ST_B(pp, (kt) + 2, 0);         \
                   PH_ST_B(pp, (kt) + 2, 1); }                                 \
    PH_MFMA(af1, bf1, 1);                                                      \
    if (dostage) { asm volatile("s_waitcnt vmcnt(6)" ::: "memory"); }          \
    else         { asm volatile("s_waitcnt vmcnt(0)" ::: "memory"); }          \
    __builtin_amdgcn_sched_barrier(0);                                         \
    __builtin_amdgcn_s_barrier();   /* next tile resident for all waves */     \
  } while (0)

#define PH_PROLOGUE()                                                          \
  do {                                                                         \
    PH_ST_A(0, 0, 0); PH_ST_A(0, 0, 1); PH_ST_A(0, 0, 2); PH_ST_A(0, 0, 3);    \
    PH_ST_B(0, 0, 0); PH_ST_B(0, 0, 1);                                        \
    PH_ST_A(1, 1, 0); PH_ST_A(1, 1, 1); PH_ST_A(1, 1, 2); PH_ST_A(1, 1, 3);    \
    PH_ST_B(1, 1, 0); PH_ST_B(1, 1, 1);                                        \
    asm volatile("s_waitcnt vmcnt(6)" ::: "memory");                           \
    __builtin_amdgcn_sched_barrier(0);                                         \
    __builtin_amdgcn_s_barrier();                                              \
  } while (0)

// gemm_o, phase-scheduled (r9): per batch C[m=query][n=d] = P . V^T; /l, fp32 out.
__launch_bounds__(512, 2)
__global__ void gemm_o(const ushort* __restrict__ Pm, const ushort* __restrict__ Vtb,
                       const float* __restrict__ l, float* __restrict__ out) {
  const int bid = blockIdx.x;
  const int b = bid & 7;             // batch -> XCD pin
  const int rowblk = (bid >> 3) & 7; // query tile 0..7 (256 rows)
  const int colblk = bid >> 6;       // d tile 0..3 (128 cols)

  extern __shared__ ushort Sd[];     // 96 KB
  ushort* SdA = Sd;
  ushort* SdB = Sd + 32768;

  const int tid = threadIdx.x;
  const int wave = tid >> 6, lane = tid & 63, quad = lane >> 4, c16 = lane & 15;
  const int wm = wave >> 1, wn = wave & 1;   // 4M x 2N; per-wave 64q x 64d

  const ushort* gA = Pm + (size_t)b * 2048 * 2048;  const int glda = 2048;
  const int arow0 = rowblk * 256;
  const ushort* gB = Vtb + (size_t)b * 512 * 2048;  const int gldb = 2048;
  const int brow0 = colblk * 128;

  f32x4 acc[4][4];
#pragma unroll
  for (int mf = 0; mf < 4; mf++)
#pragma unroll
    for (int nf = 0; nf < 4; nf++) acc[mf][nf] = (f32x4)0.0f;

  PH_PROLOGUE();
  short8 af0[4], bf0[4], af1[4], bf1[4];
  for (int i = 0; i < 16; i++) {
    const int ds = (i < 15);
    PH_TILE(0, 2 * i, ds);
    PH_TILE(1, 2 * i + 1, ds);
  }

  // Epilogue: /l, fp32 out.
  const int row0 = rowblk * 256 + wm * 64;   // query
  const int col0 = colblk * 128 + wn * 64;   // d
  float linv[4][4];
#pragma unroll
  for (int mf = 0; mf < 4; mf++)
#pragma unroll
    for (int r = 0; r < 4; r++)
      linv[mf][r] = 1.0f / l[b * 2048 + row0 + mf * 16 + quad * 4 + r];
#pragma unroll
  for (int mf = 0; mf < 4; mf++)
#pragma unroll
    for (int nf = 0; nf < 4; nf++) {
      int col = col0 + nf * 16 + c16;
#pragma unroll
      for (int r = 0; r < 4; r++) {
        int row = row0 + mf * 16 + quad * 4 + r;
        out[((size_t)b * 2048 + row) * 512 + col] = acc[mf][nf][r] * linv[mf][r];
      }
    }
}

// ---------------------------------------------------------------------------
extern "C" void kernel_launch(void* const* d_in, const int* in_sizes, int n_in,
                              void* d_out, int out_size, void* d_ws, size_t ws_size,
                              hipStream_t stream) {
  (void)in_sizes; (void)n_in; (void)out_size; (void)ws_size;
  const float* X    = (const float*)d_in[0];
  const int*   mask = (const int*)d_in[1];
  const float* Wk   = (const float*)d_in[2];
  const float* bk   = (const float*)d_in[3];
  const float* Wq   = (const float*)d_in[4];
  const float* bq   = (const float*)d_in[5];
  const float* Wv   = (const float*)d_in[6];
  const float* bv   = (const float*)d_in[7];
  float* out = (float*)d_out;

  ushort* ws  = (ushort*)d_ws;
  ushort* Pm  = ws;                             // [8][2048][2048] bf16 (64 MB)
  ushort* Xb  = ws;                             // [16384][512] aliases Pm (dead after qkv)
  ushort* Wb  = ws + (size_t)33554432;          // [1536][512]  rows = [Wq;Wk;Wv]
  ushort* Qb  = Wb + (size_t)786432;            // [16384][512] pre-scaled
  ushort* Kb  = Qb + (size_t)8388608;           // [16384][512]
  ushort* Vtb = Kb + (size_t)8388608;           // [8][512][2048]
  float*  lde = (float*)(Vtb + (size_t)8388608);// [16384] softmax denominators

  convert_all<<<8976, 256, 0, stream>>>(Wq, Wk, Wv, X, Wb, Xb, lde);
  qkv_gemm<<<dim3(128, 12), 256, 0, stream>>>(Xb, Wb, bq, bk, bv, Qb, Kb, Vtb);
  gemm_s<<<2048, 256, 0, stream>>>(Kb, Qb, mask, Pm, lde);
  gemm_o<<<256, 512, 98304, stream>>>(Pm, Vtb, lde, out);
}

// Round 12
// 196.870 us; speedup vs baseline: 1.0450x; 1.0028x over previous
//
#include <hip/hip_runtime.h>
#include <hip/hip_bf16.h>

// SelfAttention: B=8, N=2048, D=512, fp32 in/out.
// No-max softmax: P = exp(S)*mask, l = rowsum(P), O = (P.V)/l.
// Pipeline: convert_all (+lde zero) -> qkv_gemm -> gemm_s -> gemm_o.
// CONFIG = r15 (gemm_s pin+nt, qkv round-robin+nt V^T) + 3-DEEP gemm_o (r16).
// Settled lessons: r7 full fusion = barrier-bound. r8/r12 tile growth REGRESSES.
// r11: deep pipeline needs LONG K. r6 form = K=512 local optimum. r13/r14: XCD pin
// wins are producer->consumer L2 handoffs; a kernel's own write stream evicts its
// pinned reads (fix: nt stores, r15: gemm_s 54->46.5). r15 lesson: nt P pushed
// gemm_o's reads to L3 (~500cyc) but its 2-deep pipeline (vmcnt(6) ~ 1 K-tile
// ~350cyc) was sized for L2 -> gemm_o 40->48.
// r16: gemm_o 3-deep rotation buf[t%3], LDS 144KB (3x48KB), stage t+3 after tile
// t's last read barrier (t,t+3 share buf mod 3 -> race-free), ONE vmcnt(12)/K-tile
// (12 in flight = 2 K-tiles ~700cyc of cover). Tail drains 12->6->0.
// ws (ushort elems): Pm[8*2048*2048] (Xb aliases head) | Wb[1536*512] | Qb | Kb
//   | Vtb[8*512*2048] | lde[16384 f32]  ~= 113.6 MB.

typedef __attribute__((ext_vector_type(8))) short short8;   // 8 x bf16
typedef __attribute__((ext_vector_type(4))) float f32x4;    // MFMA 16x16 acc

#define DEV __device__ __forceinline__
#define GLOBAL_AS __attribute__((address_space(1)))
#define LDS_AS __attribute__((address_space(3)))

static DEV ushort f2bs(float f) {  // fp32 -> bf16 bits, RNE
  union { float f; unsigned u; } x; x.f = f;
  unsigned r = (x.u + 0x7fffu + ((x.u >> 16) & 1u)) >> 16;
  return (ushort)r;
}

static DEV f32x4 mfma16(short8 a, short8 b, f32x4 c) {
  // C[m][n] += sum_k A[m][k]*B[n][k]
  return __builtin_amdgcn_mfma_f32_16x16x32_bf16(a, b, c, 0, 0, 0);
}

static DEV void async16(const void* g, void* l) {
  __builtin_amdgcn_global_load_lds((const GLOBAL_AS void*)g, (LDS_AS void*)l, 16, 0, 0);
}

// ---------------------------------------------------------------------------
// fp32->bf16 converts (weights, X) + lde zeroing, one kernel.
__global__ void convert_all(const float* __restrict__ wq, const float* __restrict__ wk,
                            const float* __restrict__ wv, const float* __restrict__ x,
                            ushort* __restrict__ wb, ushort* __restrict__ xb,
                            float* __restrict__ lde) {
  int i = blockIdx.x * 256 + threadIdx.x;
  if (i >= 2293760) {                       // lde tail: 4096 float4 groups
    int off = (i - 2293760) * 4;
    float4 z; z.x = 0.f; z.y = 0.f; z.z = 0.f; z.w = 0.f;
    *(float4*)(lde + off) = z;
    return;
  }
  const float* src;
  ushort* dst;
  if (i < 196608) {
    int which = i >> 16;
    int off = (i & 65535) * 4;
    src = ((which == 0) ? wq : (which == 1) ? wk : wv) + off;
    dst = wb + (size_t)which * 262144 + off;
  } else {
    int off = (i - 196608) * 4;
    src = x + off;
    dst = xb + off;
  }
  float4 v = *(const float4*)src;
  ushort4 o;
  o.x = f2bs(v.x); o.y = f2bs(v.y); o.z = f2bs(v.z); o.w = f2bs(v.w);
  *(ushort4*)dst = o;
}

// ---------------------------------------------------------------------------
// Shared K-loop (BK=64): stage A/B 128x64-bf16 tiles, swizzled, then 2 k-slices.
// As/Bs rows are 128B = 8 chunks of 16B; LDS chunk c holds global chunk c^(row&7).
#define KLOOP_STAGE(Aptr, lda, Bptr, ldb)                                      \
  do {                                                                         \
    _Pragma("unroll")                                                          \
    for (int t = 0; t < 8; t++) {                                              \
      int rowbase = (t & 3) * 32 + wave * 8;                                   \
      int r = rowbase + (lane >> 3);                                           \
      int gc = (lane & 7) ^ (r & 7);                                           \
      if (t < 4)                                                               \
        async16((Aptr) + (size_t)(rowblk * 128 + r) * (lda) + kb + gc * 8,     \
                &As[rowbase * 64]);                                            \
      else                                                                     \
        async16((Bptr) + (size_t)(colblk * 128 + r) * (ldb) + kb + gc * 8,     \
                &Bs[rowbase * 64]);                                            \
    }                                                                          \
  } while (0)

#define KLOOP_MFMA()                                                           \
  do {                                                                         \
    _Pragma("unroll")                                                          \
    for (int ks = 0; ks < 2; ks++) {                                           \
      short8 af[4], bfr[4];                                                    \
      _Pragma("unroll")                                                        \
      for (int t = 0; t < 4; t++) {                                            \
        int ra = wm * 64 + t * 16 + c16;                                       \
        int rb = wn * 64 + t * 16 + c16;                                       \
        af[t]  = *(const short8*)&As[ra * 64 + (((ks * 4 + quad) ^ (ra & 7)) * 8)]; \
        bfr[t] = *(const short8*)&Bs[rb * 64 + (((ks * 4 + quad) ^ (rb & 7)) * 8)]; \
      }                                                                        \
      _Pragma("unroll")                                                        \
      for (int mt = 0; mt < 4; mt++)                                           \
        _Pragma("unroll")                                                      \
        for (int nt = 0; nt < 4; nt++)                                         \
          acc[mt][nt] = mfma16(af[mt], bfr[nt], acc[mt][nt]);                  \
    }                                                                          \
  } while (0)

// ---------------------------------------------------------------------------
// Fused QKV GEMM: C[n][eg] = sum_d X[n][d]*W[eg][d] + bias, eg in [0,1536).
// eg<512 -> Q (scaled 1/sqrt(D)), <1024 -> K, else V^T [b][d][n].  grid (128,12).
__launch_bounds__(256, 4)
__global__ void qkv_gemm(const ushort* __restrict__ Xb, const ushort* __restrict__ Wb,
                         const float* __restrict__ bq, const float* __restrict__ bk,
                         const float* __restrict__ bv,
                         ushort* __restrict__ Qb, ushort* __restrict__ Kb,
                         ushort* __restrict__ Vtb) {
  const int rowblk = blockIdx.x;      // 0..127 (token rows)
  const int colblk = blockIdx.y;      // 0..11  (output cols / 128)
  const int z = colblk >> 2;          // 0 Q, 1 K, 2 V

  __shared__ ushort S[2 * 128 * 64];  // 32 KB: As | Bs (and epilogue transpose tile)
  ushort* As = S;
  ushort* Bs = S + 128 * 64;

  const int tid = threadIdx.x;
  const int wave = tid >> 6, lane = tid & 63, quad = lane >> 4, c16 = lane & 15;
  const int wm = wave & 1, wn = wave >> 1;

  f32x4 acc[4][4];
#pragma unroll
  for (int mt = 0; mt < 4; mt++)
#pragma unroll
    for (int nt = 0; nt < 4; nt++) acc[mt][nt] = (f32x4)0.0f;

  for (int kb = 0; kb < 512; kb += 64) {
    __syncthreads();
    KLOOP_STAGE(Xb, 512, Wb, 512);
    __syncthreads();
    KLOOP_MFMA();
  }

  const float* bias = (z == 0) ? bq : (z == 1) ? bk : bv;
  float bvals[4];
#pragma unroll
  for (int nt = 0; nt < 4; nt++) {
    int eg = colblk * 128 + wn * 64 + nt * 16 + c16;
    bvals[nt] = bias[eg & 511];
  }
  const float sc = (z == 0) ? 0.044194173824159216f : 1.0f;   // 1/sqrt(512) into Q

  const int row0 = rowblk * 128 + wm * 64;
  const int col0 = colblk * 128 + wn * 64;
  if (z < 2) {
    ushort* O = (z == 0) ? Qb : Kb;
#pragma unroll
    for (int mt = 0; mt < 4; mt++)
#pragma unroll
      for (int nt = 0; nt < 4; nt++) {
        int el = (col0 + nt * 16 + c16) & 511;
#pragma unroll
        for (int r = 0; r < 4; r++) {
          int n = row0 + mt * 16 + quad * 4 + r;
          O[(size_t)n * 512 + el] = f2bs((acc[mt][nt][r] + bvals[nt]) * sc);
        }
      }
  } else {
    // V^T: transpose via LDS (dead As+Bs), then 64-B sector-complete nt stores.
    __syncthreads();                   // all waves done reading As/Bs
    ushort* T = S;                     // T[el 0..127][n 0..127], chunk-xor swizzled
#pragma unroll
    for (int nt = 0; nt < 4; nt++) {
      int ell = wn * 64 + nt * 16 + c16;       // local el
#pragma unroll
      for (int mt = 0; mt < 4; mt++) {
        int n0l = wm * 64 + mt * 16 + quad * 4; // local n (4 consecutive via r)
        ushort4 o;
        o.x = f2bs(acc[mt][nt][0] + bvals[nt]);
        o.y = f2bs(acc[mt][nt][1] + bvals[nt]);
        o.z = f2bs(acc[mt][nt][2] + bvals[nt]);
        o.w = f2bs(acc[mt][nt][3] + bvals[nt]);
        *(ushort4*)&T[ell * 128 + (((n0l >> 3) ^ (ell & 15)) << 3) + (n0l & 4)] = o;
      }
    }
    __syncthreads();
    const int c4 = tid & 3, er = tid >> 2;      // 4 lanes per row -> 64B runs
    const int bb = rowblk >> 4;
    const int nbase = (rowblk & 15) * 128;
    const int elbase = (colblk & 3) * 128;
#pragma unroll
    for (int part = 0; part < 2; part++) {
      int ell = part * 64 + er;
      size_t ge = ((size_t)bb * 512 + elbase + ell) * 2048;
#pragma unroll
      for (int j2 = 0; j2 < 4; j2++) {
        int n0 = j2 * 32 + c4 * 8;              // ushort units within the 128-n tile
        short8 v = *(short8*)&T[ell * 128 + (((n0 >> 3) ^ (ell & 15)) << 3)];
        __builtin_nontemporal_store(v, (short8*)(Vtb + ge + nbase + n0));
      }
    }
  }
}

// ---------------------------------------------------------------------------
// gemm_s: per batch, C[m=key][n=query] = K.Q^T (Q pre-scaled).  r6 body; grid:
// 2048 linear blocks, b = bid&7 (XCD pin: batch's K+Q = 4MB = one L2),
// rowblk = (bid>>3)&15 (key tile), colblk = bid>>7 (query tile).
// P stores non-temporal -> the 64MB P stream doesn't evict K/Q from L2.
__launch_bounds__(256, 4)
__global__ void gemm_s(const ushort* __restrict__ Kb, const ushort* __restrict__ Qb,
                       const int* __restrict__ mask, ushort* __restrict__ Pm,
                       float* __restrict__ l) {
  const int bid = blockIdx.x;
  const int b = bid & 7;
  const int rowblk = (bid >> 3) & 15;   // key tile
  const int colblk = bid >> 7;          // query tile
  const ushort* A  = Kb + (size_t)b * 2048 * 512;
  const ushort* Bq = Qb + (size_t)b * 2048 * 512;

  __shared__ ushort S[2 * 128 * 64];  // 32 KB
  ushort* As = S;
  ushort* Bs = S + 128 * 64;

  const int tid = threadIdx.x;
  const int wave = tid >> 6, lane = tid & 63, quad = lane >> 4, c16 = lane & 15;
  const int wm = wave & 1, wn = wave >> 1;

  f32x4 acc[4][4];
#pragma unroll
  for (int mt = 0; mt < 4; mt++)
#pragma unroll
    for (int nt = 0; nt < 4; nt++) acc[mt][nt] = (f32x4)0.0f;

  for (int kb = 0; kb < 512; kb += 64) {
    __syncthreads();
    KLOOP_STAGE(A, 512, Bq, 512);
    __syncthreads();
    KLOOP_MFMA();
  }

  const int row0 = rowblk * 128 + wm * 64;   // key base (global in batch)
  const int col0 = colblk * 128 + wn * 64;   // query base
  float lpart[4] = {0.0f, 0.0f, 0.0f, 0.0f};

  __syncthreads();                 // all waves done reading As/Bs; reuse S
  ushort* T = S;                   // T[q 0..127][key 0..127], chunk-xor swizzled
#pragma unroll
  for (int mt = 0; mt < 4; mt++) {
    int key0 = row0 + mt * 16 + quad * 4;       // global key (for mask)
    int k0l  = wm * 64 + mt * 16 + quad * 4;    // local key
    int4 mv = *(const int4*)&mask[b * 2048 + key0];
    float mf0 = mv.x ? 1.0f : 0.0f, mf1 = mv.y ? 1.0f : 0.0f;
    float mf2 = mv.z ? 1.0f : 0.0f, mf3 = mv.w ? 1.0f : 0.0f;
#pragma unroll
    for (int nt = 0; nt < 4; nt++) {
      int ql = wn * 64 + nt * 16 + c16;         // local query
      float p0 = __expf(acc[mt][nt][0]) * mf0;
      float p1 = __expf(acc[mt][nt][1]) * mf1;
      float p2 = __expf(acc[mt][nt][2]) * mf2;
      float p3 = __expf(acc[mt][nt][3]) * mf3;
      ushort4 o;
      o.x = f2bs(p0); o.y = f2bs(p1); o.z = f2bs(p2); o.w = f2bs(p3);
      *(ushort4*)&T[ql * 128 + (((k0l >> 3) ^ (ql & 15)) << 3) + (k0l & 4)] = o;
      lpart[nt] += p0 + p1 + p2 + p3;
    }
  }
#pragma unroll
  for (int nt = 0; nt < 4; nt++) {
    float v = lpart[nt];
    v += __shfl_xor(v, 16, 64);
    v += __shfl_xor(v, 32, 64);
    if (quad == 0) atomicAdd(&l[b * 2048 + col0 + nt * 16 + c16], v);
  }
  __syncthreads();
  {
    const int c4 = tid & 3, er = tid >> 2;      // 4 lanes per q-row -> 64B runs
#pragma unroll
    for (int part = 0; part < 2; part++) {
      int ql = part * 64 + er;
      size_t gq = ((size_t)b * 2048 + colblk * 128 + ql) * 2048;
#pragma unroll
      for (int j2 = 0; j2 < 4; j2++) {
        int n0 = j2 * 32 + c4 * 8;              // ushort units within 128-key tile
        short8 v = *(short8*)&T[ql * 128 + (((n0 >> 3) ^ (ql & 15)) << 3)];
        __builtin_nontemporal_store(v, (short8*)(Pm + gq + rowblk * 128 + n0));
      }
    }
  }
}

// ===========================================================================
// gemm_o phase machinery, 3-DEEP (r16): BM=256 x BN=128, 8 waves, 144KB LDS
// (3 bufs x {32KB A + 16KB B}), rotation buf[t%3], per-tile fine phases,
// stage t+3 after tile t's last read barrier, ONE counted vmcnt(12) per K-tile.
#define PH_ST_A(pp, kt, rd)                                                    \
  do {                                                                         \
    int rowbase_ = (rd) * 64 + wave * 8;                                       \
    int r_ = rowbase_ + (lane >> 3);                                           \
    int gc_ = (lane & 7) ^ (r_ & 7);                                           \
    async16(gA + (size_t)(arow0 + r_) * glda + (kt) * 64 + gc_ * 8,            \
            SdA + (pp) * 16384 + rowbase_ * 64);                               \
  } while (0)

#define PH_ST_B(pp, kt, rd)                                                    \
  do {                                                                         \
    int rowbase_ = (rd) * 64 + wave * 8;                                       \
    int r_ = rowbase_ + (lane >> 3);                                           \
    int gc_ = (lane & 7) ^ (r_ & 7);                                           \
    async16(gB + (size_t)(brow0 + r_) * gldb + (kt) * 64 + gc_ * 8,            \
            SdB + (pp) * 8192 + rowbase_ * 64);                                \
  } while (0)

#define PH_READ(pp, ks, afx, bfx)                                              \
  do {                                                                         \
    const ushort* Ap_ = SdA + (pp) * 16384;                                    \
    const ushort* Bp_ = SdB + (pp) * 8192;                                     \
    _Pragma("unroll")                                                          \
    for (int mf = 0; mf < 4; mf++) {                                           \
      int ra = wm * 64 + mf * 16 + c16;                                        \
      afx[mf] = *(const short8*)&Ap_[ra * 64 + ((((ks)*4 + quad) ^ (ra & 7)) * 8)]; \
    }                                                                          \
    _Pragma("unroll")                                                          \
    for (int nf = 0; nf < 4; nf++) {                                           \
      int rb = wn * 64 + nf * 16 + c16;                                        \
      bfx[nf] = *(const short8*)&Bp_[rb * 64 + ((((ks)*4 + quad) ^ (rb & 7)) * 8)]; \
    }                                                                          \
  } while (0)

#define PH_MFMA(afx, bfx, h)                                                   \
  do {                                                                         \
    __builtin_amdgcn_s_setprio(1);                                             \
    _Pragma("unroll")                                                          \
    for (int mf = (h) * 2; mf < (h) * 2 + 2; mf++)                             \
      _Pragma("unroll")                                                        \
      for (int nf = 0; nf < 4; nf++)                                           \
        acc[mf][nf] = mfma16(afx[mf], bfx[nf], acc[mf][nf]);                   \
    __builtin_amdgcn_s_setprio(0);                                             \
  } while (0)

#define PH_WAIT_(N) asm volatile("s_waitcnt vmcnt(" #N ")" ::: "memory")
#define PH_WAIT(N) PH_WAIT_(N)

// One K-tile: 4 fine phases; optional stage of tile kt+3 into the SAME buffer
// (legal: all waves' reads of buf pp retired at the mid barrier); wait WN at end.
#define PH_TILE3(pp, kt, dostage, WN)                                          \
  do {                                                                         \
    PH_READ(pp, 0, af0, bf0);                                                  \
    __builtin_amdgcn_s_barrier();                                              \
    asm volatile("s_waitcnt lgkmcnt(0)" ::: "memory");                         \
    __builtin_amdgcn_sched_barrier(0);                                         \
    PH_MFMA(af0, bf0, 0);                                                      \
    __builtin_amdgcn_s_barrier();                                              \
    PH_READ(pp, 1, af1, bf1);                                                  \
    __builtin_amdgcn_s_barrier();                                              \
    asm volatile("s_waitcnt lgkmcnt(0)" ::: "memory");                         \
    __builtin_amdgcn_sched_barrier(0);                                         \
    PH_MFMA(af0, bf0, 1);                                                      \
    __builtin_amdgcn_s_barrier();   /* all waves' buf-pp reads retired */      \
    if (dostage) { PH_ST_A(pp, (kt) + 3, 0); PH_ST_A(pp, (kt) + 3, 1);         \
                   PH_ST_A(pp, (kt) + 3, 2); }                                 \
    PH_MFMA(af1, bf1, 0);                                                      \
    __builtin_amdgcn_s_barrier();                                              \
    if (dostage) { PH_ST_A(pp, (kt) + 3, 3); PH_ST_B(pp, (kt) + 3, 0);         \
                   PH_ST_B(pp, (kt) + 3, 1); }                                 \
    PH_MFMA(af1, bf1, 1);                                                      \
    PH_WAIT(WN);                                                               \
    __builtin_amdgcn_sched_barrier(0);                                         \
    __builtin_amdgcn_s_barrier();   /* next tile resident for all waves */     \
  } while (0)

// Last K-tile: compute only (no stage, no wait, no trailing barrier).
#define PH_TILE3_LAST(pp)                                                      \
  do {                                                                         \
    PH_READ(pp, 0, af0, bf0);                                                  \
    __builtin_amdgcn_s_barrier();                                              \
    asm volatile("s_waitcnt lgkmcnt(0)" ::: "memory");                         \
    __builtin_amdgcn_sched_barrier(0);                                         \
    PH_MFMA(af0, bf0, 0);                                                      \
    __builtin_amdgcn_s_barrier();                                              \
    PH_READ(pp, 1, af1, bf1);                                                  \
    asm volatile("s_waitcnt lgkmcnt(0)" ::: "memory");                         \
    __builtin_amdgcn_sched_barrier(0);                                         \
    PH_MFMA(af0, bf0, 1);                                                      \
    PH_MFMA(af1, bf1, 0);                                                      \
    PH_MFMA(af1, bf1, 1);                                                      \
  } while (0)

#define PH_PROLOGUE3()                                                         \
  do {                                                                         \
    PH_ST_A(0, 0, 0); PH_ST_A(0, 0, 1); PH_ST_A(0, 0, 2); PH_ST_A(0, 0, 3);    \
    PH_ST_B(0, 0, 0); PH_ST_B(0, 0, 1);                                        \
    PH_ST_A(1, 1, 0); PH_ST_A(1, 1, 1); PH_ST_A(1, 1, 2); PH_ST_A(1, 1, 3);    \
    PH_ST_B(1, 1, 0); PH_ST_B(1, 1, 1);                                        \
    PH_ST_A(2, 2, 0); PH_ST_A(2, 2, 1); PH_ST_A(2, 2, 2); PH_ST_A(2, 2, 3);    \
    PH_ST_B(2, 2, 0); PH_ST_B(2, 2, 1);                                        \
    PH_WAIT(12);                                                               \
    __builtin_amdgcn_sched_barrier(0);                                         \
    __builtin_amdgcn_s_barrier();                                              \
  } while (0)

// gemm_o: per batch C[m=query][n=d] = P . V^T; /l, fp32 out.  NT=32 K-tiles.
__launch_bounds__(512, 2)
__global__ void gemm_o(const ushort* __restrict__ Pm, const ushort* __restrict__ Vtb,
                       const float* __restrict__ l, float* __restrict__ out) {
  const int bid = blockIdx.x;
  const int b = bid & 7;             // batch -> XCD pin
  const int rowblk = (bid >> 3) & 7; // query tile 0..7 (256 rows)
  const int colblk = bid >> 6;       // d tile 0..3 (128 cols)

  extern __shared__ ushort Sd[];     // 144 KB
  ushort* SdA = Sd;                  // [3][256*64]
  ushort* SdB = Sd + 3 * 16384;      // [3][128*64]

  const int tid = threadIdx.x;
  const int wave = tid >> 6, lane = tid & 63, quad = lane >> 4, c16 = lane & 15;
  const int wm = wave >> 1, wn = wave & 1;   // 4M x 2N; per-wave 64q x 64d

  const ushort* gA = Pm + (size_t)b * 2048 * 2048;  const int glda = 2048;
  const int arow0 = rowblk * 256;
  const ushort* gB = Vtb + (size_t)b * 512 * 2048;  const int gldb = 2048;
  const int brow0 = colblk * 128;

  f32x4 acc[4][4];
#pragma unroll
  for (int mf = 0; mf < 4; mf++)
#pragma unroll
    for (int nf = 0; nf < 4; nf++) acc[mf][nf] = (f32x4)0.0f;

  PH_PROLOGUE3();
  short8 af0[4], bf0[4], af1[4], bf1[4];
  // t = 0..26: stage t+3, vmcnt(12).  27/28: stage 30/31, vmcnt(12).
  // 29: no stage, vmcnt(6).  30: no stage, vmcnt(0).  31: compute only.
  for (int i = 0; i < 9; i++) {
    PH_TILE3(0, 3 * i,     1, 12);
    PH_TILE3(1, 3 * i + 1, 1, 12);
    PH_TILE3(2, 3 * i + 2, 1, 12);
  }
  PH_TILE3(0, 27, 1, 12);
  PH_TILE3(1, 28, 1, 12);
  PH_TILE3(2, 29, 0, 6);
  PH_TILE3(0, 30, 0, 0);
  PH_TILE3_LAST(1);

  // Epilogue: /l, fp32 out.
  const int row0 = rowblk * 256 + wm * 64;   // query
  const int col0 = colblk * 128 + wn * 64;   // d
  float linv[4][4];
#pragma unroll
  for (int mf = 0; mf < 4; mf++)
#pragma unroll
    for (int r = 0; r < 4; r++)
      linv[mf][r] = 1.0f / l[b * 2048 + row0 + mf * 16 + quad * 4 + r];
#pragma unroll
  for (int mf = 0; mf < 4; mf++)
#pragma unroll
    for (int nf = 0; nf < 4; nf++) {
      int col = col0 + nf * 16 + c16;
#pragma unroll
      for (int r = 0; r < 4; r++) {
        int row = row0 + mf * 16 + quad * 4 + r;
        out[((size_t)b * 2048 + row) * 512 + col] = acc[mf][nf][r] * linv[mf][r];
      }
    }
}

// ---------------------------------------------------------------------------
extern "C" void kernel_launch(void* const* d_in, const int* in_sizes, int n_in,
                              void* d_out, int out_size, void* d_ws, size_t ws_size,
                              hipStream_t stream) {
  (void)in_sizes; (void)n_in; (void)out_size; (void)ws_size;
  const float* X    = (const float*)d_in[0];
  const int*   mask = (const int*)d_in[1];
  const float* Wk   = (const float*)d_in[2];
  const float* bk   = (const float*)d_in[3];
  const float* Wq   = (const float*)d_in[4];
  const float* bq   = (const float*)d_in[5];
  const float* Wv   = (const float*)d_in[6];
  const float* bv   = (const float*)d_in[7];
  float* out = (float*)d_out;

  ushort* ws  = (ushort*)d_ws;
  ushort* Pm  = ws;                             // [8][2048][2048] bf16 (64 MB)
  ushort* Xb  = ws;                             // [16384][512] aliases Pm (dead after qkv)
  ushort* Wb  = ws + (size_t)33554432;          // [1536][512]  rows = [Wq;Wk;Wv]
  ushort* Qb  = Wb + (size_t)786432;            // [16384][512] pre-scaled
  ushort* Kb  = Qb + (size_t)8388608;           // [16384][512]
  ushort* Vtb = Kb + (size_t)8388608;           // [8][512][2048]
  float*  lde = (float*)(Vtb + (size_t)8388608);// [16384] softmax denominators

  convert_all<<<8976, 256, 0, stream>>>(Wq, Wk, Wv, X, Wb, Xb, lde);
  qkv_gemm<<<dim3(128, 12), 256, 0, stream>>>(Xb, Wb, bq, bk, bv, Qb, Kb, Vtb);
  gemm_s<<<2048, 256, 0, stream>>>(Kb, Qb, mask, Pm, lde);
  gemm_o<<<256, 512, 147456, stream>>>(Pm, Vtb, lde, out);
}